// Round 8
// baseline (275.177 us; speedup 1.0000x reference)
//
#include <hip/hip_runtime.h>
#include <math.h>

// Problem constants
#define B_SZ   2
#define N_TOK  2048
#define DM     512
#define NH     8
#define DHH    64
#define NF     256
#define DFF    2048
#define HF     2048    // NH*NF
#define LDQKV  1536    // fused QKV row stride

constexpr float DN_SCALE   = 0.35355339059327373f; // 64^-0.25
constexpr float DIAG_SCALE = 0.0625f;              // 0.5 * dn^2
constexpr float RATIO      = 0.0625f;              // 256^-0.5
constexpr float FEPS       = 1e-4f;
constexpr float LN_EPS     = 1e-5f;

typedef __attribute__((ext_vector_type(8))) short bf16x8;
typedef __attribute__((ext_vector_type(8))) _Float16 f16x8;
typedef __attribute__((ext_vector_type(4))) float f32x4;

__device__ __forceinline__ short f2b(float f) {
  union { float f; unsigned u; } x; x.f = f;
  unsigned r = (x.u + 0x7fff + ((x.u >> 16) & 1)) >> 16;
  return (short)r;
}
__device__ __forceinline__ float b2f(short s) {
  union { unsigned u; float f; } x; x.u = ((unsigned)(unsigned short)s) << 16;
  return x.f;
}
__device__ __forceinline__ void gload16(const void* g, void* l) {
  __builtin_amdgcn_global_load_lds((const __attribute__((address_space(1))) void*)g,
                                   (__attribute__((address_space(3))) void*)l, 16, 0, 0);
}
__device__ __forceinline__ int swz64(int row, int kbyte) {
  return (row * 128 + kbyte) ^ ((row & 7) << 4);
}
__device__ __forceinline__ float reduce_bmax512(const float* __restrict__ bmax,
                                                float* __restrict__ red) {
  int t = threadIdx.x;
  float m = fmaxf(bmax[t], bmax[t + 256]);
  #pragma unroll
  for (int o = 1; o < 64; o <<= 1) m = fmaxf(m, __shfl_xor(m, o, 64));
  if ((t & 63) == 0) red[t >> 6] = m;
  __syncthreads();
  float r = fmaxf(fmaxf(red[0], red[1]), fmaxf(red[2], red[3]));
  __syncthreads();
  return r;
}

// Workspace layout (float-offset units)
constexpr size_t OFF_CTXP  = 0;              // fp32 8x[16][256][64] = 2097152
constexpr size_t OFF_QB    = 4194304;        // bf16 [2,2048,2048]
constexpr size_t OFF_OUT2  = 0;              // fp32 [4096,512]  (after ctxp dead)
constexpr size_t OFF_FF1B  = 2097152;        // bf16 [4096,2048] (after qb dead)
constexpr size_t OFF_FF2   = 6291456;        // fp32 [4096,512]
constexpr size_t OFF_QFB   = 8388608;        // bf16 [2,2048,2048]; earlier: xb
constexpr size_t OFF_KB    = 12582912;       // bf16 e=exp(dd-diag); earlier: Wqkvt
constexpr size_t OFF_QKV   = 16777216;       // fp32 [4096,1536]
constexpr size_t OFF_AOB   = 20971520;       // bf16 [4096,512]
constexpr size_t OFF_H1B   = 22020096;       // bf16 [4096,512]
constexpr size_t OFF_WOT   = 23068672;       // bf16 [512,512]
constexpr size_t OFF_W1T   = 23199744;       // bf16 [2048,512]
constexpr size_t OFF_W2T   = 23724032;       // bf16 [512,2048]
constexpr size_t OFF_KSUM  = 24248320;       // [16,256] affine-applied
constexpr size_t OFF_DINV  = 24252416;       // [16,2048]
constexpr size_t OFF_CTXT  = 24285184;       // bf16 ctxT [16,64,256]
constexpr size_t OFF_BMAX  = 24416256;       // [512]
constexpr size_t OFF_ROWC  = 24416832;       // [4096]
constexpr size_t OFF_PART  = 24420928;       // [16,32,256] col sums of e
constexpr size_t OFF_VSUMP = 24552000;       // [8,16,64]

// ---------------- device tile bodies ----------------

// attnw 128x128 tile: C[z] = qb[z] @ kb[z]^T + rowc[z][row]
__device__ __forceinline__ void attnw_tile(short* As, short* Bs, int flat, int z,
                                           const short* __restrict__ qb,
                                           const short* __restrict__ kb,
                                           const float* __restrict__ rowc,
                                           float* __restrict__ attnw) {
  int tid = threadIdx.x, lane = tid & 63, wave = tid >> 6;
  int srow = tid >> 3, scol = (tid & 7) * 8;
  int tile = flat >> 4, wi = flat & 15;
  int by = (tile >> 2) * 4 + (wi >> 2);
  int bx = (tile & 3) * 4 + (wi & 3);
  int bm = by * 128, bn = bx * 128;
  const short* Ab = qb + (size_t)z * N_TOK * HF;
  const short* Bb = kb + (size_t)z * N_TOK * HF;
  const float* rc = rowc + (size_t)z * N_TOK;
  float* out = attnw + (size_t)z * N_TOK * N_TOK;
  int wm = wave >> 1, wn = wave & 1;

  f32x4 acc[4][4] = {};
  for (int k0 = 0; k0 < HF; k0 += 64) {
    #pragma unroll
    for (int c = 0; c < 4; ++c) {
      int r = c * 32 + srow;
      gload16(Ab + (size_t)(bm + r) * HF + k0 + scol, As + c * 2048 + wave * 512);
      gload16(Bb + (size_t)(bn + r) * HF + k0 + scol, Bs + c * 2048 + wave * 512);
    }
    __syncthreads();
    #pragma unroll
    for (int kk = 0; kk < 2; ++kk) {
      bf16x8 af[4], bf[4];
      int kq = kk * 32 + (lane >> 4) * 8;
      #pragma unroll
      for (int i = 0; i < 4; ++i)
        af[i] = *(const bf16x8*)&As[(wm * 64 + i * 16 + (lane & 15)) * 64 + kq];
      #pragma unroll
      for (int j = 0; j < 4; ++j)
        bf[j] = *(const bf16x8*)&Bs[(wn * 64 + j * 16 + (lane & 15)) * 64 + kq];
      #pragma unroll
      for (int i = 0; i < 4; ++i)
        #pragma unroll
        for (int j = 0; j < 4; ++j)
          acc[i][j] = __builtin_amdgcn_mfma_f32_16x16x32_bf16(af[i], bf[j], acc[i][j], 0, 0, 0);
    }
    __syncthreads();
  }
  int row0 = bm + wm * 64, col0 = bn + wn * 64;
  #pragma unroll
  for (int i = 0; i < 4; ++i) {
    #pragma unroll
    for (int j = 0; j < 4; ++j) {
      int col = col0 + j * 16 + (lane & 15);
      #pragma unroll
      for (int r = 0; r < 4; ++r) {
        int row = row0 + i * 16 + (lane >> 4) * 4 + r;
        out[(size_t)row * N_TOK + col] = acc[i][j][r] + rc[row];
      }
    }
  }
}

// pv tile: aob = Dinv * (qfb @ ctxT^T)
__device__ __forceinline__ void pv_tile(short* As, short* Bs, int pid,
                                        const short* __restrict__ qfb,
                                        const short* __restrict__ ctxT,
                                        const float* __restrict__ Dinv,
                                        short* __restrict__ aob) {
  int tid = threadIdx.x, lane = tid & 63, wave = tid >> 6;
  int srow = tid >> 3, scol = (tid & 7) * 8;
  int bx = pid & 15, bh = pid >> 4;
  int b = bh >> 3, h = bh & 7;
  int n0 = bx * 128;

  f32x4 acc[2][4] = {};
  for (int k0 = 0; k0 < NF; k0 += 64) {
    #pragma unroll
    for (int c = 0; c < 4; ++c) {
      int r = c * 32 + srow;
      gload16(qfb + (size_t)(b * N_TOK + n0 + r) * HF + h * NF + k0 + scol,
              As + c * 2048 + wave * 512);
    }
    #pragma unroll
    for (int c = 0; c < 2; ++c) {
      int r = c * 32 + srow;
      gload16(ctxT + (size_t)bh * 16384 + (size_t)r * 256 + k0 + scol,
              Bs + c * 2048 + wave * 512);
    }
    __syncthreads();
    #pragma unroll
    for (int kk = 0; kk < 2; ++kk) {
      bf16x8 af[2], bf[4];
      int kq = kk * 32 + (lane >> 4) * 8;
      #pragma unroll
      for (int i = 0; i < 2; ++i)
        af[i] = *(const bf16x8*)&As[(wave * 32 + i * 16 + (lane & 15)) * 64 + kq];
      #pragma unroll
      for (int j = 0; j < 4; ++j)
        bf[j] = *(const bf16x8*)&Bs[(j * 16 + (lane & 15)) * 64 + kq];
      #pragma unroll
      for (int i = 0; i < 2; ++i)
        #pragma unroll
        for (int j = 0; j < 4; ++j)
          acc[i][j] = __builtin_amdgcn_mfma_f32_16x16x32_bf16(af[i], bf[j], acc[i][j], 0, 0, 0);
    }
    __syncthreads();
  }
  #pragma unroll
  for (int i = 0; i < 2; ++i) {
    #pragma unroll
    for (int j = 0; j < 4; ++j) {
      int e = j * 16 + (lane & 15);
      #pragma unroll
      for (int r = 0; r < 4; ++r) {
        int n = n0 + wave * 32 + i * 16 + (lane >> 4) * 4 + r;
        float dv = Dinv[bh * N_TOK + n];
        aob[(size_t)(b * N_TOK + n) * DM + h * DHH + e] = f2b(acc[i][j][r] * dv);
      }
    }
  }
}

// bn64 tile: C[M,N] = A[M,K] @ Bt[N,K]^T + bias (N=512 geometry via params)
template<bool RELU, bool OUT_BF16>
__device__ __forceinline__ void bn64_tile(short* As, short* Bs, int bn, int bm,
                                          const short* __restrict__ A,
                                          const short* __restrict__ Bt,
                                          const float* __restrict__ bias,
                                          void* __restrict__ Cout, int N, int K) {
  int tid = threadIdx.x, lane = tid & 63, wave = tid >> 6;
  int srow = tid >> 3, scol = (tid & 7) * 8;
  f32x4 acc[2][4] = {};
  for (int k0 = 0; k0 < K; k0 += 64) {
    #pragma unroll
    for (int c = 0; c < 4; ++c)
      gload16(A + (size_t)(bm + c * 32 + srow) * K + k0 + scol, As + c * 2048 + wave * 512);
    #pragma unroll
    for (int c = 0; c < 2; ++c)
      gload16(Bt + (size_t)(bn + c * 32 + srow) * K + k0 + scol, Bs + c * 2048 + wave * 512);
    __syncthreads();
    #pragma unroll
    for (int kk = 0; kk < 2; ++kk) {
      bf16x8 af[2], bf[4];
      int kq = kk * 32 + (lane >> 4) * 8;
      #pragma unroll
      for (int i = 0; i < 2; ++i)
        af[i] = *(const bf16x8*)&As[(wave * 32 + i * 16 + (lane & 15)) * 64 + kq];
      #pragma unroll
      for (int j = 0; j < 4; ++j)
        bf[j] = *(const bf16x8*)&Bs[(j * 16 + (lane & 15)) * 64 + kq];
      #pragma unroll
      for (int i = 0; i < 2; ++i)
        #pragma unroll
        for (int j = 0; j < 4; ++j)
          acc[i][j] = __builtin_amdgcn_mfma_f32_16x16x32_bf16(af[i], bf[j], acc[i][j], 0, 0, 0);
    }
    __syncthreads();
  }
  #pragma unroll
  for (int i = 0; i < 2; ++i) {
    #pragma unroll
    for (int j = 0; j < 4; ++j) {
      int col = bn + j * 16 + (lane & 15);
      float bv = bias[col];
      #pragma unroll
      for (int r = 0; r < 4; ++r) {
        int row = bm + wave * 32 + i * 16 + (lane >> 4) * 4 + r;
        float v = acc[i][j][r] + bv;
        if (RELU) v = fmaxf(v, 0.f);
        if (OUT_BF16) ((short*)Cout)[(size_t)row * N + col] = f2b(v);
        else          ((float*)Cout)[(size_t)row * N + col] = v;
      }
    }
  }
}

// ---------------- kernels ----------------

// FAT1: bid 0..255 attnw z=0; 256..511 pv
__global__ __launch_bounds__(256)
void fat1_kernel(const short* __restrict__ qb, const short* __restrict__ kb,
                 const float* __restrict__ rowc, float* __restrict__ attnw,
                 const short* __restrict__ qfb, const short* __restrict__ ctxT,
                 const float* __restrict__ Dinv, short* __restrict__ aob) {
  __shared__ short As[128 * 64];
  __shared__ short Bs[128 * 64];
  int bid = blockIdx.x;
  if (bid < 256) attnw_tile(As, Bs, bid, 0, qb, kb, rowc, attnw);
  else           pv_tile(As, Bs, bid - 256, qfb, ctxT, Dinv, aob);
}

// FAT2: bid 0..255 attnw z=1; 256..511 Wo projection
__global__ __launch_bounds__(256)
void fat2_kernel(const short* __restrict__ qb, const short* __restrict__ kb,
                 const float* __restrict__ rowc, float* __restrict__ attnw,
                 const short* __restrict__ aob, const short* __restrict__ Wot,
                 const float* __restrict__ bo, float* __restrict__ out2) {
  __shared__ short As[128 * 64];
  __shared__ short Bs[128 * 64];
  int bid = blockIdx.x;
  if (bid < 256) {
    attnw_tile(As, Bs, bid, 1, qb, kb, rowc, attnw);
  } else {
    int pid = bid - 256;
    bn64_tile<false, false>(As, Bs, (pid & 7) * 64, (pid >> 3) * 128,
                            aob, Wot, bo, out2, DM, DM);
  }
}

// generic BN=64 GEMM launcher form (for ff2)
template<bool RELU, bool OUT_BF16>
__global__ __launch_bounds__(256)
void gemm_bn64(const short* __restrict__ A, const short* __restrict__ Bt,
               const float* __restrict__ bias, void* __restrict__ Cout,
               int M, int N, int K) {
  __shared__ short As[128 * 64];
  __shared__ short Bs[64 * 64];
  bn64_tile<RELU, OUT_BF16>(As, Bs, blockIdx.x * 64, blockIdx.y * 128, A, Bt, bias, Cout, N, K);
}

// ============ bf16 MFMA GEMM (m97): C = A[M,K] @ Bt[N,K]^T
template<bool RELU, bool OUT_BF16, int BMODE>
__global__ __launch_bounds__(256)
void gemm_mfma(const short* __restrict__ A, const short* __restrict__ Bt,
               const float* __restrict__ bias, void* __restrict__ Cout,
               int M, int N, int K, int ldC) {
  __shared__ short As[128 * 64];
  __shared__ short Bs[128 * 64];
  int tid = threadIdx.x;
  int lane = tid & 63, wave = tid >> 6;
  int wm = wave >> 1, wn = wave & 1;
  int bm = blockIdx.y * 128, bn = blockIdx.x * 128;

  f32x4 acc[4][4] = {};
  int srow = tid >> 3;
  int scol = (tid & 7) * 8;

  for (int k0 = 0; k0 < K; k0 += 64) {
    #pragma unroll
    for (int c = 0; c < 4; ++c) {
      int r = c * 32 + srow;
      gload16(A + (size_t)(bm + r) * K + k0 + scol, As + c * 2048 + wave * 512);
      gload16(Bt + (size_t)(bn + r) * K + k0 + scol, Bs + c * 2048 + wave * 512);
    }
    __syncthreads();
    #pragma unroll
    for (int kk = 0; kk < 2; ++kk) {
      bf16x8 af[4], bf[4];
      int kq = kk * 32 + (lane >> 4) * 8;
      #pragma unroll
      for (int i = 0; i < 4; ++i)
        af[i] = *(const bf16x8*)&As[(wm * 64 + i * 16 + (lane & 15)) * 64 + kq];
      #pragma unroll
      for (int j = 0; j < 4; ++j)
        bf[j] = *(const bf16x8*)&Bs[(wn * 64 + j * 16 + (lane & 15)) * 64 + kq];
      #pragma unroll
      for (int i = 0; i < 4; ++i)
        #pragma unroll
        for (int j = 0; j < 4; ++j)
          acc[i][j] = __builtin_amdgcn_mfma_f32_16x16x32_bf16(af[i], bf[j], acc[i][j], 0, 0, 0);
    }
    __syncthreads();
  }

  int row0 = bm + wm * 64, col0 = bn + wn * 64;
  #pragma unroll
  for (int i = 0; i < 4; ++i) {
    #pragma unroll
    for (int j = 0; j < 4; ++j) {
      int col = col0 + j * 16 + (lane & 15);
      float bv = (BMODE == 1) ? bias[col] : 0.f;
      #pragma unroll
      for (int r = 0; r < 4; ++r) {
        int row = row0 + i * 16 + (lane >> 4) * 4 + r;
        float v = acc[i][j][r] + bv;
        if (RELU) v = fmaxf(v, 0.f);
        size_t off = (size_t)row * ldC + col;
        if (OUT_BF16) ((short*)Cout)[off] = f2b(v);
        else          ((float*)Cout)[off] = v;
      }
    }
  }
}

// ============ fused prep: x->bf16 + all 6 weight transposes
__global__ void prep_kernel(const float* __restrict__ x, short* __restrict__ xb,
                            const float* Wq, const float* Wk, const float* Wv, const float* Wo,
                            short* Wqt, short* Wkt, short* Wvt, short* Wot,
                            const float* W1, short* W1t, const float* W2, short* W2t) {
  __shared__ float t[64][65];
  int id = blockIdx.x, tid = threadIdx.x;
  if (id >= 768) {
    size_t base = ((size_t)(id - 768) * 256 + tid) * 8;
    #pragma unroll
    for (int u = 0; u < 8; ++u) xb[base + u] = f2b(x[base + u]);
    return;
  }
  const float* W; short* Wt; int K, N, bx, by;
  if (id < 256) {
    int z = id >> 6, sub = id & 63;
    W  = (z == 0) ? Wq : (z == 1) ? Wk : (z == 2) ? Wv : Wo;
    Wt = (z == 0) ? Wqt : (z == 1) ? Wkt : (z == 2) ? Wvt : Wot;
    K = 512; N = 512; bx = sub & 7; by = sub >> 3;
  } else if (id < 512) {
    int sub = id - 256;
    W = W1; Wt = W1t; K = 512; N = 2048; bx = sub & 31; by = sub >> 5;
  } else {
    int sub = id - 512;
    W = W2; Wt = W2t; K = 2048; N = 512; bx = sub & 7; by = sub >> 3;
  }
  int k0 = by * 64, n0 = bx * 64;
  int lx = tid & 63, ly = tid >> 6;
  for (int r = ly; r < 64; r += 4)
    t[r][lx] = W[(size_t)(k0 + r) * N + n0 + lx];
  __syncthreads();
  for (int r = ly; r < 64; r += 4)
    Wt[(size_t)(n0 + r) * K + k0 + lx] = f2b(t[lx][r]);
}

// ============ feature maps, Q and K in one launch (z=0: Q, z=1: K)
__global__ __launch_bounds__(256)
void feat_mfma_kernel(const float* __restrict__ qkv, const float* __restrict__ bq,
                      const float* __restrict__ bk, const float* __restrict__ proj,
                      short* __restrict__ qfb, short* __restrict__ kbo,
                      float* __restrict__ part, float* __restrict__ bmax) {
  __shared__ short qh[64 * 64], ql[64 * 64];
  __shared__ short ph[128 * 64], pl[128 * 64];
  __shared__ float dpart[64][4];
  __shared__ float diag[64];
  __shared__ float wred[4];
  __shared__ float colp[4][256];
  int t = threadIdx.x;
  bool isq = (blockIdx.z == 0);
  int coff = isq ? 0 : 512;
  const float* bias = isq ? bq : bk;
  short* qout = isq ? qfb : kbo;
  int bh = blockIdx.y, b = bh >> 3, h = bh & 7;
  int n0 = blockIdx.x * 64;
  int lane = t & 63, w = t >> 6, l15 = lane & 15, lq = lane >> 4;

  {
    int r = t >> 2, cg = (t & 3) * 16;
    const float* src = qkv + (size_t)(b * N_TOK + n0 + r) * LDQKV + coff + h * 64 + cg;
    const float* bs = bias + h * 64 + cg;
    float ss = 0.f;
    #pragma unroll
    for (int c2 = 0; c2 < 2; ++c2) {
      f16x8 H, L;
      #pragma unroll
      for (int u = 0; u < 8; ++u) {
        float xv = src[c2 * 8 + u] + bs[c2 * 8 + u];
        ss += xv * xv;
        _Float16 hi = (_Float16)xv;
        H[u] = hi;
        L[u] = (_Float16)(xv - (float)hi);
      }
      int off = swz64(r, cg * 2 + c2 * 16);
      *(f16x8*)((char*)qh + off) = H;
      *(f16x8*)((char*)ql + off) = L;
    }
    dpart[r][t & 3] = ss;
  }
  __syncthreads();
  if (t < 64)
    diag[t] = (dpart[t][0] + dpart[t][1] + dpart[t][2] + dpart[t][3]) * DIAG_SCALE;

  f16x8 ah[2], al[2];
  #pragma unroll
  for (int kk = 0; kk < 2; ++kk) {
    int off = swz64(w * 16 + l15, kk * 64 + lq * 16);
    ah[kk] = *(f16x8*)((char*)qh + off);
    al[kk] = *(f16x8*)((char*)ql + off);
  }

  f32x4 acc[16] = {};
  #pragma unroll
  for (int half = 0; half < 2; ++half) {
    __syncthreads();
    {
      int r = t & 127, cg = (t >> 7) * 32;
      const float* src = proj + (size_t)(half * 128 + r) * DHH + cg;
      #pragma unroll
      for (int c2 = 0; c2 < 4; ++c2) {
        f16x8 H, L;
        #pragma unroll
        for (int u = 0; u < 8; ++u) {
          float xv = src[c2 * 8 + u];
          _Float16 hi = (_Float16)xv;
          H[u] = hi;
          L[u] = (_Float16)(xv - (float)hi);
        }
        int off = swz64(r, cg * 2 + c2 * 16);
        *(f16x8*)((char*)ph + off) = H;
        *(f16x8*)((char*)pl + off) = L;
      }
    }
    __syncthreads();
    #pragma unroll
    for (int jl = 0; jl < 8; ++jl) {
      int row = jl * 16 + l15;
      #pragma unroll
      for (int kk = 0; kk < 2; ++kk) {
        int off = swz64(row, kk * 64 + lq * 16);
        f16x8 bh8 = *(f16x8*)((char*)ph + off);
        f16x8 bl8 = *(f16x8*)((char*)pl + off);
        acc[half * 8 + jl] = __builtin_amdgcn_mfma_f32_16x16x32_f16(ah[kk], bh8, acc[half * 8 + jl], 0, 0, 0);
        acc[half * 8 + jl] = __builtin_amdgcn_mfma_f32_16x16x32_f16(al[kk], bh8, acc[half * 8 + jl], 0, 0, 0);
        acc[half * 8 + jl] = __builtin_amdgcn_mfma_f32_16x16x32_f16(ah[kk], bl8, acc[half * 8 + jl], 0, 0, 0);
      }
    }
  }

  if (isq) {
    #pragma unroll
    for (int r = 0; r < 4; ++r) {
      float mx = -3.4e38f;
      #pragma unroll
      for (int j = 0; j < 16; ++j) mx = fmaxf(mx, acc[j][r]);
      #pragma unroll
      for (int o = 1; o < 16; o <<= 1) mx = fmaxf(mx, __shfl_xor(mx, o, 64));
      int lrow = w * 16 + lq * 4 + r;
      float dg = diag[lrow];
      float ddm = mx * DN_SCALE;
      size_t base = (size_t)(b * N_TOK + n0 + lrow) * HF + h * NF + l15;
      #pragma unroll
      for (int j = 0; j < 16; ++j) {
        float v = RATIO * (expf(acc[j][r] * DN_SCALE - dg - ddm) + FEPS);
        qout[base + j * 16] = f2b(v);
      }
    }
  } else {
    float mxall = -3.4e38f;
    float cs[16];
    #pragma unroll
    for (int j = 0; j < 16; ++j) cs[j] = 0.f;
    #pragma unroll
    for (int r = 0; r < 4; ++r) {
      int lrow = w * 16 + lq * 4 + r;
      float dg = diag[lrow];
      size_t base = (size_t)(b * N_TOK + n0 + lrow) * HF + h * NF + l15;
      #pragma unroll
      for (int j = 0; j < 16; ++j) {
        float a = acc[j][r];
        mxall = fmaxf(mxall, a);
        float e = expf(a * DN_SCALE - dg);
        cs[j] += e;
        qout[base + j * 16] = f2b(e);
      }
    }
    #pragma unroll
    for (int j = 0; j < 16; ++j) {
      cs[j] += __shfl_xor(cs[j], 16, 64);
      cs[j] += __shfl_xor(cs[j], 32, 64);
    }
    if (lq == 0) {
      #pragma unroll
      for (int j = 0; j < 16; ++j) colp[w][j * 16 + l15] = cs[j];
    }
    #pragma unroll
    for (int o = 1; o < 64; o <<= 1) mxall = fmaxf(mxall, __shfl_xor(mxall, o, 64));
    if (lane == 0) wred[w] = mxall;
    __syncthreads();
    part[(size_t)(bh * 32 + blockIdx.x) * 256 + t] =
        colp[0][t] + colp[1][t] + colp[2][t] + colp[3][t];
    if (t == 0)
      bmax[bh * 32 + blockIdx.x] =
          fmaxf(fmaxf(wred[0], wred[1]), fmaxf(wred[2], wred[3])) * DN_SCALE;
  }
}

// ============ ctx partial over 256-row n-chunks; x-block 0 also sums V columns
__global__ __launch_bounds__(256)
void ctx_part_kernel(const short* __restrict__ kb, const float* __restrict__ qkv,
                     const float* __restrict__ bv, float* __restrict__ ctxp,
                     float* __restrict__ vsump) {
  int bh = blockIdx.y, b = bh >> 3, h = bh & 7;
  int f0 = blockIdx.x * 64;
  int ns = blockIdx.z * 256;
  __shared__ float kf[32][68];
  __shared__ float vs[32][68];
  int tid = threadIdx.x;
  int tf = (tid >> 4) * 4, te = (tid & 15) * 4;
  float acc[4][4] = {};
  float vloc[4] = {};
  for (int n0 = ns; n0 < ns + 256; n0 += 32) {
    #pragma unroll
    for (int i = 0; i < 8; i++) {
      int idx = tid + i * 256;
      int nn = idx >> 6, f = idx & 63;
      kf[nn][f] = b2f(kb[(size_t)(b * N_TOK + n0 + nn) * HF + h * NF + f0 + f]);
    }
    #pragma unroll
    for (int i = 0; i < 8; i++) {
      int idx = tid + i * 256;
      int nn = idx >> 6, e = idx & 63;
      vs[nn][e] = qkv[(size_t)(b * N_TOK + n0 + nn) * LDQKV + 1024 + h * DHH + e] + bv[h * DHH + e];
    }
    __syncthreads();
    #pragma unroll
    for (int nn = 0; nn < 32; nn++) {
      float a[4], bb[4];
      #pragma unroll
      for (int i = 0; i < 4; i++) a[i] = kf[nn][tf + i];
      #pragma unroll
      for (int j = 0; j < 4; j++) bb[j] = vs[nn][te + j];
      #pragma unroll
      for (int i = 0; i < 4; i++)
        #pragma unroll
        for (int j = 0; j < 4; j++) acc[i][j] += a[i] * bb[j];
    }
    if (blockIdx.x == 0 && (tid >> 4) == 0) {
      #pragma unroll
      for (int j = 0; j < 4; j++) {
        float s = 0.f;
        for (int nn = 0; nn < 32; nn++) s += vs[nn][te + j];
        vloc[j] += s;
      }
    }
    __syncthreads();
  }
  #pragma unroll
  for (int i = 0; i < 4; i++)
    #pragma unroll
    for (int j = 0; j < 4; j++)
      ctxp[(size_t)blockIdx.z * 262144 + (size_t)bh * 16384 +
           (size_t)(f0 + tf + i) * 64 + te + j] = acc[i][j];
  if (blockIdx.x == 0 && (tid >> 4) == 0) {
    #pragma unroll
    for (int j = 0; j < 4; j++)
      vsump[((size_t)blockIdx.z * 16 + bh) * 64 + te + j] = vloc[j];
  }
}

// ============ small fat: blocks 0..15 = ksum finalize; 16..79 = ctx reduce+transpose
__global__ __launch_bounds__(256)
void smallfat_kernel(const float* __restrict__ part, const float* __restrict__ bmax,
                     float* __restrict__ ksum, const float* __restrict__ ctxp,
                     const float* __restrict__ vsump, short* __restrict__ ctxT) {
  __shared__ float T[64][65];
  __shared__ float red[4];
  int t = threadIdx.x;
  float m = reduce_bmax512(bmax, red);
  float s = expf(-m);
  if (blockIdx.x < 16) {
    int bh = blockIdx.x;
    float sum = 0.f;
    #pragma unroll 8
    for (int c = 0; c < 32; ++c) sum += part[(size_t)(bh * 32 + c) * 256 + t];
    ksum[bh * 256 + t] = RATIO * (s * sum + (float)N_TOK * FEPS);
  } else {
    int id = blockIdx.x - 16;
    int ftile = id & 3, bh = id >> 2;
    int e = t & 63, q = t >> 6;
    float vsum_e = 0.f;
    #pragma unroll
    for (int c = 0; c < 8; ++c) vsum_e += vsump[((size_t)c * 16 + bh) * 64 + e];
    #pragma unroll
    for (int i = 0; i < 16; ++i) {
      int fl = i * 4 + q;
      size_t idx = (size_t)bh * 16384 + (size_t)(ftile * 64 + fl) * 64 + e;
      float sum = 0.f;
      #pragma unroll
      for (int c = 0; c < 8; ++c) sum += ctxp[(size_t)c * 262144 + idx];
      T[fl][e] = RATIO * (s * sum + FEPS * vsum_e);
    }
    __syncthreads();
    #pragma unroll
    for (int i = 0; i < 16; ++i) {
      int er = i * 4 + q;
      ctxT[(size_t)bh * 16384 + (size_t)er * 256 + ftile * 64 + e] = f2b(T[e][er]);
    }
  }
}

// ============ fused D_inv + q-scale + row constant
__global__ __launch_bounds__(256)
void dinvqs_kernel(const short* __restrict__ qfb, const float* __restrict__ ksum,
                   const float* __restrict__ bmax, float* __restrict__ Dinv,
                   float* __restrict__ rowc, short* __restrict__ qb) {
  __shared__ float red[4];
  __shared__ float wsum[4];
  int R = blockIdx.x;
  int b = R >> 11, n = R & 2047;
  int t = threadIdx.x;
  float m = reduce_bmax512(bmax, red);
  float sc = RATIO * expf(-m);
  bf16x8 qv = *(const bf16x8*)(qfb + (size_t)R * HF + t * 8);
  const float* ks = ksum + b * 2048 + t * 8;
  float p = 0.f;
  #pragma unroll
  for (int u = 0; u < 8; ++u) p += b2f(qv[u]) * ks[u];
  #pragma unroll
  for (int o = 1; o < 32; o <<= 1) p += __shfl_xor(p, o, 64);
  float d = 1.0f / p;
  if ((t & 31) == 0) Dinv[(b * NH + (t >> 5)) * N_TOK + n] = d;
  float dv = d * 0.125f;
  float qs = 0.f;
  bf16x8 o8;
  #pragma unroll
  for (int u = 0; u < 8; ++u) {
    float qb_f = b2f(qv[u]) * dv;
    qs += qb_f;
    o8[u] = f2b(qb_f * sc);
  }
  *(bf16x8*)(qb + (size_t)R * HF + t * 8) = o8;
  #pragma unroll
  for (int o = 1; o < 64; o <<= 1) qs += __shfl_xor(qs, o, 64);
  if ((t & 63) == 0) wsum[t >> 6] = qs;
  __syncthreads();
  if (t == 0) rowc[R] = RATIO * FEPS * (wsum[0] + wsum[1] + wsum[2] + wsum[3]);
}

// ============ LayerNorm over D=512
template<bool OUT_BF16>
__global__ void ln_kernel(const float* __restrict__ x, const float* __restrict__ g,
                          const float* __restrict__ beta, void* __restrict__ y) {
  int row = blockIdx.x, t = threadIdx.x;
  __shared__ float red[4];
  __shared__ float bcast[2];
  const float* xr = x + (size_t)row * DM;
  float v0 = xr[t], v1 = xr[t + 256];
  float s = v0 + v1;
  #pragma unroll
  for (int o = 32; o > 0; o >>= 1) s += __shfl_xor(s, o, 64);
  if ((t & 63) == 0) red[t >> 6] = s;
  __syncthreads();
  if (t == 0) bcast[0] = (red[0] + red[1] + red[2] + red[3]) * (1.0f / 512.0f);
  __syncthreads();
  float mean = bcast[0];
  float d0 = v0 - mean, d1 = v1 - mean;
  float s2 = d0 * d0 + d1 * d1;
  #pragma unroll
  for (int o = 32; o > 0; o >>= 1) s2 += __shfl_xor(s2, o, 64);
  if ((t & 63) == 0) red[t >> 6] = s2;
  __syncthreads();
  if (t == 0) bcast[1] = (red[0] + red[1] + red[2] + red[3]) * (1.0f / 512.0f);
  __syncthreads();
  float inv = rsqrtf(bcast[1] + LN_EPS);
  float o0 = g[t] * d0 * inv + beta[t];
  float o1 = g[t + 256] * d1 * inv + beta[t + 256];
  if (OUT_BF16) {
    ((short*)y)[(size_t)row * DM + t] = f2b(o0);
    ((short*)y)[(size_t)row * DM + t + 256] = f2b(o1);
  } else {
    ((float*)y)[(size_t)row * DM + t] = o0;
    ((float*)y)[(size_t)row * DM + t + 256] = o1;
  }
}

extern "C" void kernel_launch(void* const* d_in, const int* in_sizes, int n_in,
                              void* d_out, int out_size, void* d_ws, size_t ws_size,
                              hipStream_t stream) {
  const float* x     = (const float*)d_in[0];
  const float* Wq    = (const float*)d_in[1];
  const float* bq    = (const float*)d_in[2];
  const float* Wk    = (const float*)d_in[3];
  const float* bk    = (const float*)d_in[4];
  const float* Wv    = (const float*)d_in[5];
  const float* bv    = (const float*)d_in[6];
  const float* Wo    = (const float*)d_in[7];
  const float* bo    = (const float*)d_in[8];
  const float* proj  = (const float*)d_in[9];
  const float* W1    = (const float*)d_in[10];
  const float* b1    = (const float*)d_in[11];
  const float* W2    = (const float*)d_in[12];
  const float* b2    = (const float*)d_in[13];
  const float* g1    = (const float*)d_in[14];
  const float* beta1 = (const float*)d_in[15];
  const float* g2    = (const float*)d_in[16];
  const float* beta2 = (const float*)d_in[17];

  float* ws = (float*)d_ws;
  float* y_out = (float*)d_out;
  float* attnw = y_out + (size_t)B_SZ * N_TOK * DM;

  float* ctxp  = ws + OFF_CTXP;
  short* qb    = (short*)(ws + OFF_QB);
  float* out2  = ws + OFF_OUT2;
  short* ff1b  = (short*)(ws + OFF_FF1B);
  float* ff2   = ws + OFF_FF2;
  short* qfb   = (short*)(ws + OFF_QFB);
  short* xb    = (short*)(ws + OFF_QFB);      // before qfb written
  short* kb    = (short*)(ws + OFF_KB);       // e = exp(dd - diag)
  short* Wqkvt = (short*)(ws + OFF_KB);       // before kb written
  float* QKVlin = ws + OFF_QKV;
  short* aob   = (short*)(ws + OFF_AOB);
  short* h1b   = (short*)(ws + OFF_H1B);
  short* Wot   = (short*)(ws + OFF_WOT);
  short* W1t   = (short*)(ws + OFF_W1T);
  short* W2t   = (short*)(ws + OFF_W2T);
  float* ksum  = ws + OFF_KSUM;
  float* Dinv  = ws + OFF_DINV;
  short* ctxT  = (short*)(ws + OFF_CTXT);
  float* bmax  = ws + OFF_BMAX;
  float* rowc  = ws + OFF_ROWC;
  float* part  = ws + OFF_PART;
  float* vsump = ws + OFF_VSUMP;

  dim3 blk(256);
  int MT = B_SZ * N_TOK;

  // 0) prep: cvt + all weight transposes
  prep_kernel<<<1792, blk, 0, stream>>>(x, xb, Wq, Wk, Wv, Wo,
                                        Wqkvt, Wqkvt + 262144, Wqkvt + 524288, Wot,
                                        W1, W1t, W2, W2t);

  // 1) fused QKV projection: QKVlin [4096,1536] fp32 (biases deferred)
  gemm_mfma<false, false, 0><<<dim3(LDQKV / 128, MT / 128), blk, 0, stream>>>(
      xb, Wqkvt, nullptr, QKVlin, MT, LDQKV, DM, LDQKV);

  // 2) feature maps Q+K in one launch
  feat_mfma_kernel<<<dim3(N_TOK / 64, B_SZ * NH, 2), blk, 0, stream>>>(
      QKVlin, bq, bk, proj, qfb, kb, part, bmax);

  // 3) ctx partials
  ctx_part_kernel<<<dim3(NF / 64, B_SZ * NH, 8), blk, 0, stream>>>(kb, QKVlin, bv, ctxp, vsump);

  // 4) ksum finalize + ctx reduce in one launch
  smallfat_kernel<<<80, blk, 0, stream>>>(part, bmax, ksum, ctxp, vsump, ctxT);

  // 5) fused D_inv + q-scale + rowc
  dinvqs_kernel<<<MT, blk, 0, stream>>>(qfb, ksum, bmax, Dinv, rowc, qb);

  // 6) FAT1: attnw z=0 (256) + pv (256)
  fat1_kernel<<<512, blk, 0, stream>>>(qb, kb, rowc, attnw, qfb, ctxT, Dinv, aob);

  // 7) FAT2: attnw z=1 (256) + Wo projection (256)
  fat2_kernel<<<512, blk, 0, stream>>>(qb, kb, rowc, attnw, aob, Wot, bo, out2);

  // 8) FFN
  ln_kernel<true><<<MT, blk, 0, stream>>>(out2, g1, beta1, h1b);
  gemm_mfma<true, true, 1><<<dim3(DFF / 128, MT / 128), blk, 0, stream>>>(
      h1b, W1t, b1, ff1b, MT, DFF, DM, DFF);
  gemm_bn64<false, false><<<dim3(DM / 64, MT / 128), blk, 0, stream>>>(
      ff1b, W2t, b2, ff2, MT, DM, DFF);
  ln_kernel<false><<<MT, blk, 0, stream>>>(ff2, g2, beta2, y_out);
}

// Round 10
// 217.212 us; speedup vs baseline: 1.2669x; 1.2669x over previous
//
#include <hip/hip_runtime.h>
#include <math.h>

// Problem constants
#define B_SZ   2
#define N_TOK  2048
#define DM     512
#define NH     8
#define DHH    64
#define NF     256
#define DFF    2048
#define HF     2048    // NH*NF
#define LDQKV  1536    // fused QKV row stride

constexpr float DN_SCALE   = 0.35355339059327373f; // 64^-0.25
constexpr float DIAG_SCALE = 0.0625f;              // 0.5 * dn^2
constexpr float RATIO      = 0.0625f;              // 256^-0.5
constexpr float FEPS       = 1e-4f;
constexpr float LN_EPS     = 1e-5f;

typedef __attribute__((ext_vector_type(8))) short bf16x8;
typedef __attribute__((ext_vector_type(8))) _Float16 f16x8;
typedef __attribute__((ext_vector_type(4))) float f32x4;

__device__ __forceinline__ short f2b(float f) {
  union { float f; unsigned u; } x; x.f = f;
  unsigned r = (x.u + 0x7fff + ((x.u >> 16) & 1)) >> 16;
  return (short)r;
}
__device__ __forceinline__ float b2f(short s) {
  union { unsigned u; float f; } x; x.u = ((unsigned)(unsigned short)s) << 16;
  return x.f;
}
__device__ __forceinline__ void gload16(const void* g, void* l) {
  __builtin_amdgcn_global_load_lds((const __attribute__((address_space(1))) void*)g,
                                   (__attribute__((address_space(3))) void*)l, 16, 0, 0);
}
__device__ __forceinline__ int swz64(int row, int kbyte) {
  return (row * 128 + kbyte) ^ ((row & 7) << 4);
}
__device__ __forceinline__ float reduce_bmax512(const float* __restrict__ bmax,
                                                float* __restrict__ red) {
  int t = threadIdx.x;
  float m = fmaxf(bmax[t], bmax[t + 256]);
  #pragma unroll
  for (int o = 1; o < 64; o <<= 1) m = fmaxf(m, __shfl_xor(m, o, 64));
  if ((t & 63) == 0) red[t >> 6] = m;
  __syncthreads();
  float r = fmaxf(fmaxf(red[0], red[1]), fmaxf(red[2], red[3]));
  __syncthreads();
  return r;
}

// Workspace layout (float-offset units)
// Timeline audit (step written -> last read):
//   ctxp   [0..4.2M)        w:3  r:4
//   out2   [0..2.1M)        w:7  r:8   (ctxp dead)
//   ff2    [0..2.1M)        w:10 r:11  (out2 dead after 8)
//   qb     [4.2M..8.4M)     w:5  r:9,10 (attnw)  -- nothing may alias until after 10
//   ff1b   [16.78M..20.97M) w:9  r:10  (QKVlin dead after 3)
constexpr size_t OFF_CTXP  = 0;              // fp32 16x[16][256][64] = 4194304
constexpr size_t OFF_QB    = 4194304;        // bf16 [2,2048,2048] (4.2M..8.4M floats)
constexpr size_t OFF_OUT2  = 0;              // fp32 [4096,512]
constexpr size_t OFF_FF2   = 0;              // fp32 [4096,512] (after out2 dead)
constexpr size_t OFF_QFB   = 8388608;        // bf16 [2,2048,2048]; earlier: xb
constexpr size_t OFF_KB    = 12582912;       // bf16 e=exp(dd-diag); earlier: Wqkvt
constexpr size_t OFF_QKV   = 16777216;       // fp32 [4096,1536]
constexpr size_t OFF_FF1B  = 16777216;       // bf16 [4096,2048] overlay of dead QKVlin
constexpr size_t OFF_AOB   = 20971520;       // bf16 [4096,512]
constexpr size_t OFF_H1B   = 22020096;       // bf16 [4096,512]
constexpr size_t OFF_WOT   = 23068672;       // bf16 [512,512]
constexpr size_t OFF_W1T   = 23199744;       // bf16 [2048,512]
constexpr size_t OFF_W2T   = 23724032;       // bf16 [512,2048]
constexpr size_t OFF_KSUM  = 24248320;       // [16,256]
constexpr size_t OFF_DINV  = 24252416;       // [16,2048]
constexpr size_t OFF_CTXT  = 24285184;       // bf16 ctxT [16,64,256]
constexpr size_t OFF_BMAX  = 24416256;       // [512]
constexpr size_t OFF_ROWC  = 24416832;       // [4096]
constexpr size_t OFF_PART  = 24420928;       // [16,32,256]
constexpr size_t OFF_VSUMP = 24552000;       // [16,16,64]

// ---------------- device tile bodies ----------------

// generic 128x128 MFMA tile: C = A[M,K] @ Bt[N,K]^T (+colbias, relu)
template<bool RELU, bool OUT_BF16, bool BIAS>
__device__ __forceinline__ void gemm128_tile(short* As, short* Bs, int bx, int by,
                                             const short* __restrict__ A,
                                             const short* __restrict__ Bt,
                                             const float* __restrict__ bias,
                                             void* __restrict__ Cout, int K, int ldC) {
  int tid = threadIdx.x, lane = tid & 63, wave = tid >> 6;
  int wm = wave >> 1, wn = wave & 1;
  int bm = by * 128, bn = bx * 128;
  int srow = tid >> 3, scol = (tid & 7) * 8;
  f32x4 acc[4][4] = {};
  for (int k0 = 0; k0 < K; k0 += 64) {
    #pragma unroll
    for (int c = 0; c < 4; ++c) {
      int r = c * 32 + srow;
      gload16(A + (size_t)(bm + r) * K + k0 + scol, As + c * 2048 + wave * 512);
      gload16(Bt + (size_t)(bn + r) * K + k0 + scol, Bs + c * 2048 + wave * 512);
    }
    __syncthreads();
    #pragma unroll
    for (int kk = 0; kk < 2; ++kk) {
      bf16x8 af[4], bf[4];
      int kq = kk * 32 + (lane >> 4) * 8;
      #pragma unroll
      for (int i = 0; i < 4; ++i)
        af[i] = *(const bf16x8*)&As[(wm * 64 + i * 16 + (lane & 15)) * 64 + kq];
      #pragma unroll
      for (int j = 0; j < 4; ++j)
        bf[j] = *(const bf16x8*)&Bs[(wn * 64 + j * 16 + (lane & 15)) * 64 + kq];
      #pragma unroll
      for (int i = 0; i < 4; ++i)
        #pragma unroll
        for (int j = 0; j < 4; ++j)
          acc[i][j] = __builtin_amdgcn_mfma_f32_16x16x32_bf16(af[i], bf[j], acc[i][j], 0, 0, 0);
    }
    __syncthreads();
  }
  int row0 = bm + wm * 64, col0 = bn + wn * 64;
  #pragma unroll
  for (int i = 0; i < 4; ++i) {
    #pragma unroll
    for (int j = 0; j < 4; ++j) {
      int col = col0 + j * 16 + (lane & 15);
      float bv = BIAS ? bias[col] : 0.f;
      #pragma unroll
      for (int r = 0; r < 4; ++r) {
        int row = row0 + i * 16 + (lane >> 4) * 4 + r;
        float v = acc[i][j][r] + bv;
        if (RELU) v = fmaxf(v, 0.f);
        size_t off = (size_t)row * ldC + col;
        if (OUT_BF16) ((short*)Cout)[off] = f2b(v);
        else          ((float*)Cout)[off] = v;
      }
    }
  }
}

// attnw 128x128 tile: C[z] = qb[z] @ kb[z]^T + rowc[z][row]
__device__ __forceinline__ void attnw_tile(short* As, short* Bs, int flat, int z,
                                           const short* __restrict__ qb,
                                           const short* __restrict__ kb,
                                           const float* __restrict__ rowc,
                                           float* __restrict__ attnw) {
  int tid = threadIdx.x, lane = tid & 63, wave = tid >> 6;
  int srow = tid >> 3, scol = (tid & 7) * 8;
  int tile = flat >> 4, wi = flat & 15;
  int by = (tile >> 2) * 4 + (wi >> 2);
  int bx = (tile & 3) * 4 + (wi & 3);
  int bm = by * 128, bn = bx * 128;
  const short* Ab = qb + (size_t)z * N_TOK * HF;
  const short* Bb = kb + (size_t)z * N_TOK * HF;
  const float* rc = rowc + (size_t)z * N_TOK;
  float* out = attnw + (size_t)z * N_TOK * N_TOK;
  int wm = wave >> 1, wn = wave & 1;

  f32x4 acc[4][4] = {};
  for (int k0 = 0; k0 < HF; k0 += 64) {
    #pragma unroll
    for (int c = 0; c < 4; ++c) {
      int r = c * 32 + srow;
      gload16(Ab + (size_t)(bm + r) * HF + k0 + scol, As + c * 2048 + wave * 512);
      gload16(Bb + (size_t)(bn + r) * HF + k0 + scol, Bs + c * 2048 + wave * 512);
    }
    __syncthreads();
    #pragma unroll
    for (int kk = 0; kk < 2; ++kk) {
      bf16x8 af[4], bf[4];
      int kq = kk * 32 + (lane >> 4) * 8;
      #pragma unroll
      for (int i = 0; i < 4; ++i)
        af[i] = *(const bf16x8*)&As[(wm * 64 + i * 16 + (lane & 15)) * 64 + kq];
      #pragma unroll
      for (int j = 0; j < 4; ++j)
        bf[j] = *(const bf16x8*)&Bs[(wn * 64 + j * 16 + (lane & 15)) * 64 + kq];
      #pragma unroll
      for (int i = 0; i < 4; ++i)
        #pragma unroll
        for (int j = 0; j < 4; ++j)
          acc[i][j] = __builtin_amdgcn_mfma_f32_16x16x32_bf16(af[i], bf[j], acc[i][j], 0, 0, 0);
    }
    __syncthreads();
  }
  int row0 = bm + wm * 64, col0 = bn + wn * 64;
  #pragma unroll
  for (int i = 0; i < 4; ++i) {
    #pragma unroll
    for (int j = 0; j < 4; ++j) {
      int col = col0 + j * 16 + (lane & 15);
      #pragma unroll
      for (int r = 0; r < 4; ++r) {
        int row = row0 + i * 16 + (lane >> 4) * 4 + r;
        out[(size_t)row * N_TOK + col] = acc[i][j][r] + rc[row];
      }
    }
  }
}

// bn64 tile: C[M,N] = A[M,K] @ Bt[N,K]^T + bias
template<bool RELU, bool OUT_BF16>
__device__ __forceinline__ void bn64_tile(short* As, short* Bs, int bn, int bm,
                                          const short* __restrict__ A,
                                          const short* __restrict__ Bt,
                                          const float* __restrict__ bias,
                                          void* __restrict__ Cout, int N, int K) {
  int tid = threadIdx.x, lane = tid & 63, wave = tid >> 6;
  int srow = tid >> 3, scol = (tid & 7) * 8;
  f32x4 acc[2][4] = {};
  for (int k0 = 0; k0 < K; k0 += 64) {
    #pragma unroll
    for (int c = 0; c < 4; ++c)
      gload16(A + (size_t)(bm + c * 32 + srow) * K + k0 + scol, As + c * 2048 + wave * 512);
    #pragma unroll
    for (int c = 0; c < 2; ++c)
      gload16(Bt + (size_t)(bn + c * 32 + srow) * K + k0 + scol, Bs + c * 2048 + wave * 512);
    __syncthreads();
    #pragma unroll
    for (int kk = 0; kk < 2; ++kk) {
      bf16x8 af[2], bf[4];
      int kq = kk * 32 + (lane >> 4) * 8;
      #pragma unroll
      for (int i = 0; i < 2; ++i)
        af[i] = *(const bf16x8*)&As[(wave * 32 + i * 16 + (lane & 15)) * 64 + kq];
      #pragma unroll
      for (int j = 0; j < 4; ++j)
        bf[j] = *(const bf16x8*)&Bs[(j * 16 + (lane & 15)) * 64 + kq];
      #pragma unroll
      for (int i = 0; i < 2; ++i)
        #pragma unroll
        for (int j = 0; j < 4; ++j)
          acc[i][j] = __builtin_amdgcn_mfma_f32_16x16x32_bf16(af[i], bf[j], acc[i][j], 0, 0, 0);
    }
    __syncthreads();
  }
  #pragma unroll
  for (int i = 0; i < 2; ++i) {
    #pragma unroll
    for (int j = 0; j < 4; ++j) {
      int col = bn + j * 16 + (lane & 15);
      float bv = bias[col];
      #pragma unroll
      for (int r = 0; r < 4; ++r) {
        int row = bm + wave * 32 + i * 16 + (lane >> 4) * 4 + r;
        float v = acc[i][j][r] + bv;
        if (RELU) v = fmaxf(v, 0.f);
        if (OUT_BF16) ((short*)Cout)[(size_t)row * N + col] = f2b(v);
        else          ((float*)Cout)[(size_t)row * N + col] = v;
      }
    }
  }
}

// pv tile: aob = Dinv * (qfb @ ctxT^T)
__device__ __forceinline__ void pv_tile(short* As, short* Bs, int pid,
                                        const short* __restrict__ qfb,
                                        const short* __restrict__ ctxT,
                                        const float* __restrict__ Dinv,
                                        short* __restrict__ aob) {
  int tid = threadIdx.x, lane = tid & 63, wave = tid >> 6;
  int srow = tid >> 3, scol = (tid & 7) * 8;
  int bx = pid & 15, bh = pid >> 4;
  int b = bh >> 3, h = bh & 7;
  int n0 = bx * 128;

  f32x4 acc[2][4] = {};
  for (int k0 = 0; k0 < NF; k0 += 64) {
    #pragma unroll
    for (int c = 0; c < 4; ++c) {
      int r = c * 32 + srow;
      gload16(qfb + (size_t)(b * N_TOK + n0 + r) * HF + h * NF + k0 + scol,
              As + c * 2048 + wave * 512);
    }
    #pragma unroll
    for (int c = 0; c < 2; ++c) {
      int r = c * 32 + srow;
      gload16(ctxT + (size_t)bh * 16384 + (size_t)r * 256 + k0 + scol,
              Bs + c * 2048 + wave * 512);
    }
    __syncthreads();
    #pragma unroll
    for (int kk = 0; kk < 2; ++kk) {
      bf16x8 af[2], bf[4];
      int kq = kk * 32 + (lane >> 4) * 8;
      #pragma unroll
      for (int i = 0; i < 2; ++i)
        af[i] = *(const bf16x8*)&As[(wave * 32 + i * 16 + (lane & 15)) * 64 + kq];
      #pragma unroll
      for (int j = 0; j < 4; ++j)
        bf[j] = *(const bf16x8*)&Bs[(j * 16 + (lane & 15)) * 64 + kq];
      #pragma unroll
      for (int i = 0; i < 2; ++i)
        #pragma unroll
        for (int j = 0; j < 4; ++j)
          acc[i][j] = __builtin_amdgcn_mfma_f32_16x16x32_bf16(af[i], bf[j], acc[i][j], 0, 0, 0);
    }
    __syncthreads();
  }
  #pragma unroll
  for (int i = 0; i < 2; ++i) {
    #pragma unroll
    for (int j = 0; j < 4; ++j) {
      int e = j * 16 + (lane & 15);
      #pragma unroll
      for (int r = 0; r < 4; ++r) {
        int n = n0 + wave * 32 + i * 16 + (lane >> 4) * 4 + r;
        float dv = Dinv[bh * N_TOK + n];
        aob[(size_t)(b * N_TOK + n) * DM + h * DHH + e] = f2b(acc[i][j][r] * dv);
      }
    }
  }
}

// ---------------- kernels ----------------

__global__ __launch_bounds__(256)
void gemm_mfma_qkv(const short* __restrict__ A, const short* __restrict__ Bt,
                   float* __restrict__ Cout) {
  __shared__ short As[128 * 64];
  __shared__ short Bs[128 * 64];
  gemm128_tile<false, false, false>(As, Bs, blockIdx.x, blockIdx.y, A, Bt, nullptr,
                                    Cout, DM, LDQKV);
}

__global__ __launch_bounds__(256)
void pv_kernel(const short* __restrict__ qfb, const short* __restrict__ ctxT,
               const float* __restrict__ Dinv, short* __restrict__ aob) {
  __shared__ short As[128 * 64];
  __shared__ short Bs[64 * 64];
  pv_tile(As, Bs, blockIdx.x, qfb, ctxT, Dinv, aob);
}

__global__ __launch_bounds__(256)
void gemm_bn64_wo(const short* __restrict__ A, const short* __restrict__ Bt,
                  const float* __restrict__ bias, float* __restrict__ Cout) {
  __shared__ short As[128 * 64];
  __shared__ short Bs[64 * 64];
  bn64_tile<false, false>(As, Bs, blockIdx.x * 64, blockIdx.y * 128, A, Bt, bias, Cout, DM, DM);
}

// fatB1: bid<256 attnw z=0; else ff1 (128^2 relu bf16). ff1b must NOT alias qb!
__global__ __launch_bounds__(256)
void fatB1_kernel(const short* __restrict__ qb, const short* __restrict__ kb,
                  const float* __restrict__ rowc, float* __restrict__ attnw,
                  const short* __restrict__ h1b, const short* __restrict__ W1t,
                  const float* __restrict__ b1, short* __restrict__ ff1b) {
  __shared__ short As[128 * 64];
  __shared__ short Bs[128 * 64];
  int bid = blockIdx.x;
  if (bid < 256) {
    attnw_tile(As, Bs, bid, 0, qb, kb, rowc, attnw);
  } else {
    int flat = bid - 256;
    gemm128_tile<true, true, true>(As, Bs, flat & 15, flat >> 4, h1b, W1t, b1, ff1b,
                                   DM, DFF);
  }
}

// fatB2: bid<256 attnw z=1; else ff2 (bn64)
__global__ __launch_bounds__(256)
void fatB2_kernel(const short* __restrict__ qb, const short* __restrict__ kb,
                  const float* __restrict__ rowc, float* __restrict__ attnw,
                  const short* __restrict__ ff1b, const short* __restrict__ W2t,
                  const float* __restrict__ b2, float* __restrict__ ff2) {
  __shared__ short As[128 * 64];
  __shared__ short Bs[128 * 64];
  int bid = blockIdx.x;
  if (bid < 256) {
    attnw_tile(As, Bs, bid, 1, qb, kb, rowc, attnw);
  } else {
    int pid = bid - 256;
    bn64_tile<false, false>(As, Bs, (pid & 7) * 64, (pid >> 3) * 128,
                            ff1b, W2t, b2, ff2, DM, DFF);
  }
}

// ============ fused prep: x->bf16 + all 6 weight transposes
__global__ void prep_kernel(const float* __restrict__ x, short* __restrict__ xb,
                            const float* Wq, const float* Wk, const float* Wv, const float* Wo,
                            short* Wqt, short* Wkt, short* Wvt, short* Wot,
                            const float* W1, short* W1t, const float* W2, short* W2t) {
  __shared__ float t[64][65];
  int id = blockIdx.x, tid = threadIdx.x;
  if (id >= 768) {
    size_t base = ((size_t)(id - 768) * 256 + tid) * 8;
    #pragma unroll
    for (int u = 0; u < 8; ++u) xb[base + u] = f2b(x[base + u]);
    return;
  }
  const float* W; short* Wt; int K, N, bx, by;
  if (id < 256) {
    int z = id >> 6, sub = id & 63;
    W  = (z == 0) ? Wq : (z == 1) ? Wk : (z == 2) ? Wv : Wo;
    Wt = (z == 0) ? Wqt : (z == 1) ? Wkt : (z == 2) ? Wvt : Wot;
    K = 512; N = 512; bx = sub & 7; by = sub >> 3;
  } else if (id < 512) {
    int sub = id - 256;
    W = W1; Wt = W1t; K = 512; N = 2048; bx = sub & 31; by = sub >> 5;
  } else {
    int sub = id - 512;
    W = W2; Wt = W2t; K = 2048; N = 512; bx = sub & 7; by = sub >> 3;
  }
  int k0 = by * 64, n0 = bx * 64;
  int lx = tid & 63, ly = tid >> 6;
  for (int r = ly; r < 64; r += 4)
    t[r][lx] = W[(size_t)(k0 + r) * N + n0 + lx];
  __syncthreads();
  for (int r = ly; r < 64; r += 4)
    Wt[(size_t)(n0 + r) * K + k0 + lx] = f2b(t[lx][r]);
}

// ============ feature maps, Q and K in one launch (z=0: Q, z=1: K)
__global__ __launch_bounds__(256)
void feat_mfma_kernel(const float* __restrict__ qkv, const float* __restrict__ bq,
                      const float* __restrict__ bk, const float* __restrict__ proj,
                      short* __restrict__ qfb, short* __restrict__ kbo,
                      float* __restrict__ part, float* __restrict__ bmax) {
  __shared__ short qh[64 * 64], ql[64 * 64];
  __shared__ short ph[128 * 64], pl[128 * 64];
  __shared__ float dpart[64][4];
  __shared__ float diag[64];
  __shared__ float wred[4];
  __shared__ float colp[4][256];
  int t = threadIdx.x;
  bool isq = (blockIdx.z == 0);
  int coff = isq ? 0 : 512;
  const float* bias = isq ? bq : bk;
  short* qout = isq ? qfb : kbo;
  int bh = blockIdx.y, b = bh >> 3, h = bh & 7;
  int n0 = blockIdx.x * 64;
  int lane = t & 63, w = t >> 6, l15 = lane & 15, lq = lane >> 4;

  {
    int r = t >> 2, cg = (t & 3) * 16;
    const float* src = qkv + (size_t)(b * N_TOK + n0 + r) * LDQKV + coff + h * 64 + cg;
    const float* bs = bias + h * 64 + cg;
    float ss = 0.f;
    #pragma unroll
    for (int c2 = 0; c2 < 2; ++c2) {
      f16x8 H, L;
      #pragma unroll
      for (int u = 0; u < 8; ++u) {
        float xv = src[c2 * 8 + u] + bs[c2 * 8 + u];
        ss += xv * xv;
        _Float16 hi = (_Float16)xv;
        H[u] = hi;
        L[u] = (_Float16)(xv - (float)hi);
      }
      int off = swz64(r, cg * 2 + c2 * 16);
      *(f16x8*)((char*)qh + off) = H;
      *(f16x8*)((char*)ql + off) = L;
    }
    dpart[r][t & 3] = ss;
  }
  __syncthreads();
  if (t < 64)
    diag[t] = (dpart[t][0] + dpart[t][1] + dpart[t][2] + dpart[t][3]) * DIAG_SCALE;

  f16x8 ah[2], al[2];
  #pragma unroll
  for (int kk = 0; kk < 2; ++kk) {
    int off = swz64(w * 16 + l15, kk * 64 + lq * 16);
    ah[kk] = *(f16x8*)((char*)qh + off);
    al[kk] = *(f16x8*)((char*)ql + off);
  }

  f32x4 acc[16] = {};
  #pragma unroll
  for (int half = 0; half < 2; ++half) {
    __syncthreads();
    {
      int r = t & 127, cg = (t >> 7) * 32;
      const float* src = proj + (size_t)(half * 128 + r) * DHH + cg;
      #pragma unroll
      for (int c2 = 0; c2 < 4; ++c2) {
        f16x8 H, L;
        #pragma unroll
        for (int u = 0; u < 8; ++u) {
          float xv = src[c2 * 8 + u];
          _Float16 hi = (_Float16)xv;
          H[u] = hi;
          L[u] = (_Float16)(xv - (float)hi);
        }
        int off = swz64(r, cg * 2 + c2 * 16);
        *(f16x8*)((char*)ph + off) = H;
        *(f16x8*)((char*)pl + off) = L;
      }
    }
    __syncthreads();
    #pragma unroll
    for (int jl = 0; jl < 8; ++jl) {
      int row = jl * 16 + l15;
      #pragma unroll
      for (int kk = 0; kk < 2; ++kk) {
        int off = swz64(row, kk * 64 + lq * 16);
        f16x8 bh8 = *(f16x8*)((char*)ph + off);
        f16x8 bl8 = *(f16x8*)((char*)pl + off);
        acc[half * 8 + jl] = __builtin_amdgcn_mfma_f32_16x16x32_f16(ah[kk], bh8, acc[half * 8 + jl], 0, 0, 0);
        acc[half * 8 + jl] = __builtin_amdgcn_mfma_f32_16x16x32_f16(al[kk], bh8, acc[half * 8 + jl], 0, 0, 0);
        acc[half * 8 + jl] = __builtin_amdgcn_mfma_f32_16x16x32_f16(ah[kk], bl8, acc[half * 8 + jl], 0, 0, 0);
      }
    }
  }

  if (isq) {
    #pragma unroll
    for (int r = 0; r < 4; ++r) {
      float mx = -3.4e38f;
      #pragma unroll
      for (int j = 0; j < 16; ++j) mx = fmaxf(mx, acc[j][r]);
      #pragma unroll
      for (int o = 1; o < 16; o <<= 1) mx = fmaxf(mx, __shfl_xor(mx, o, 64));
      int lrow = w * 16 + lq * 4 + r;
      float dg = diag[lrow];
      float ddm = mx * DN_SCALE;
      size_t base = (size_t)(b * N_TOK + n0 + lrow) * HF + h * NF + l15;
      #pragma unroll
      for (int j = 0; j < 16; ++j) {
        float v = RATIO * (expf(acc[j][r] * DN_SCALE - dg - ddm) + FEPS);
        qout[base + j * 16] = f2b(v);
      }
    }
  } else {
    float mxall = -3.4e38f;
    float cs[16];
    #pragma unroll
    for (int j = 0; j < 16; ++j) cs[j] = 0.f;
    #pragma unroll
    for (int r = 0; r < 4; ++r) {
      int lrow = w * 16 + lq * 4 + r;
      float dg = diag[lrow];
      size_t base = (size_t)(b * N_TOK + n0 + lrow) * HF + h * NF + l15;
      #pragma unroll
      for (int j = 0; j < 16; ++j) {
        float a = acc[j][r];
        mxall = fmaxf(mxall, a);
        float e = expf(a * DN_SCALE - dg);
        cs[j] += e;
        qout[base + j * 16] = f2b(e);
      }
    }
    #pragma unroll
    for (int j = 0; j < 16; ++j) {
      cs[j] += __shfl_xor(cs[j], 16, 64);
      cs[j] += __shfl_xor(cs[j], 32, 64);
    }
    if (lq == 0) {
      #pragma unroll
      for (int j = 0; j < 16; ++j) colp[w][j * 16 + l15] = cs[j];
    }
    #pragma unroll
    for (int o = 1; o < 64; o <<= 1) mxall = fmaxf(mxall, __shfl_xor(mxall, o, 64));
    if (lane == 0) wred[w] = mxall;
    __syncthreads();
    part[(size_t)(bh * 32 + blockIdx.x) * 256 + t] =
        colp[0][t] + colp[1][t] + colp[2][t] + colp[3][t];
    if (t == 0)
      bmax[bh * 32 + blockIdx.x] =
          fmaxf(fmaxf(wred[0], wred[1]), fmaxf(wred[2], wred[3])) * DN_SCALE;
  }
}

// ============ ctx partial over 128-row n-chunks (lean); x==4 blocks do V col-sums
__global__ __launch_bounds__(256)
void ctx_part_kernel(const short* __restrict__ kb, const float* __restrict__ qkv,
                     const float* __restrict__ bv, float* __restrict__ ctxp,
                     float* __restrict__ vsump) {
  int bh = blockIdx.y, b = bh >> 3, h = bh & 7;
  int ns = blockIdx.z * 128;
  int tid = threadIdx.x;
  if (blockIdx.x == 4) {
    __shared__ float vred[4][64];
    int e = tid & 63, q = tid >> 6;
    float s = 0.f;
    for (int nn = q * 32; nn < q * 32 + 32; ++nn)
      s += qkv[(size_t)(b * N_TOK + ns + nn) * LDQKV + 1024 + h * DHH + e];
    vred[q][e] = s;
    __syncthreads();
    if (tid < 64)
      vsump[((size_t)blockIdx.z * 16 + bh) * 64 + tid] =
          vred[0][tid] + vred[1][tid] + vred[2][tid] + vred[3][tid] + 128.f * bv[h * DHH + tid];
    return;
  }
  int f0 = blockIdx.x * 64;
  __shared__ float kf[32][68];
  __shared__ float vs[32][68];
  int tf = (tid >> 4) * 4, te = (tid & 15) * 4;
  float acc[4][4] = {};
  for (int n0 = ns; n0 < ns + 128; n0 += 32) {
    #pragma unroll
    for (int i = 0; i < 8; i++) {
      int idx = tid + i * 256;
      int nn = idx >> 6, f = idx & 63;
      kf[nn][f] = b2f(kb[(size_t)(b * N_TOK + n0 + nn) * HF + h * NF + f0 + f]);
    }
    #pragma unroll
    for (int i = 0; i < 8; i++) {
      int idx = tid + i * 256;
      int nn = idx >> 6, e = idx & 63;
      vs[nn][e] = qkv[(size_t)(b * N_TOK + n0 + nn) * LDQKV + 1024 + h * DHH + e] + bv[h * DHH + e];
    }
    __syncthreads();
    #pragma unroll
    for (int nn = 0; nn < 32; nn++) {
      float a[4], bb[4];
      #pragma unroll
      for (int i = 0; i < 4; i++) a[i] = kf[nn][tf + i];
      #pragma unroll
      for (int j = 0; j < 4; j++) bb[j] = vs[nn][te + j];
      #pragma unroll
      for (int i = 0; i < 4; i++)
        #pragma unroll
        for (int j = 0; j < 4; j++) acc[i][j] += a[i] * bb[j];
    }
    __syncthreads();
  }
  #pragma unroll
  for (int i = 0; i < 4; i++)
    #pragma unroll
    for (int j = 0; j < 4; j++)
      ctxp[(size_t)blockIdx.z * 262144 + (size_t)bh * 16384 +
           (size_t)(f0 + tf + i) * 64 + te + j] = acc[i][j];
}

// ============ small fat: blocks 0..15 = ksum finalize; 16..79 = ctx reduce+transpose
__global__ __launch_bounds__(256)
void smallfat_kernel(const float* __restrict__ part, const float* __restrict__ bmax,
                     float* __restrict__ ksum, const float* __restrict__ ctxp,
                     const float* __restrict__ vsump, short* __restrict__ ctxT) {
  __shared__ float T[64][65];
  __shared__ float red[4];
  int t = threadIdx.x;
  float m = reduce_bmax512(bmax, red);
  float s = expf(-m);
  if (blockIdx.x < 16) {
    int bh = blockIdx.x;
    float sum = 0.f;
    #pragma unroll 8
    for (int c = 0; c < 32; ++c) sum += part[(size_t)(bh * 32 + c) * 256 + t];
    ksum[bh * 256 + t] = RATIO * (s * sum + (float)N_TOK * FEPS);
  } else {
    int id = blockIdx.x - 16;
    int ftile = id & 3, bh = id >> 2;
    int e = t & 63, q = t >> 6;
    float vsum_e = 0.f;
    #pragma unroll
    for (int c = 0; c < 16; ++c) vsum_e += vsump[((size_t)c * 16 + bh) * 64 + e];
    #pragma unroll
    for (int i = 0; i < 16; ++i) {
      int fl = i * 4 + q;
      size_t idx = (size_t)bh * 16384 + (size_t)(ftile * 64 + fl) * 64 + e;
      float sum = 0.f;
      #pragma unroll
      for (int c = 0; c < 16; ++c) sum += ctxp[(size_t)c * 262144 + idx];
      T[fl][e] = RATIO * (s * sum + FEPS * vsum_e);
    }
    __syncthreads();
    #pragma unroll
    for (int i = 0; i < 16; ++i) {
      int er = i * 4 + q;
      ctxT[(size_t)bh * 16384 + (size_t)er * 256 + ftile * 64 + e] = f2b(T[e][er]);
    }
  }
}

// ============ fused D_inv + q-scale + row constant
__global__ __launch_bounds__(256)
void dinvqs_kernel(const short* __restrict__ qfb, const float* __restrict__ ksum,
                   const float* __restrict__ bmax, float* __restrict__ Dinv,
                   float* __restrict__ rowc, short* __restrict__ qb) {
  __shared__ float red[4];
  __shared__ float wsum[4];
  int R = blockIdx.x;
  int b = R >> 11, n = R & 2047;
  int t = threadIdx.x;
  float m = reduce_bmax512(bmax, red);
  float sc = RATIO * expf(-m);
  bf16x8 qv = *(const bf16x8*)(qfb + (size_t)R * HF + t * 8);
  const float* ks = ksum + b * 2048 + t * 8;
  float p = 0.f;
  #pragma unroll
  for (int u = 0; u < 8; ++u) p += b2f(qv[u]) * ks[u];
  #pragma unroll
  for (int o = 1; o < 32; o <<= 1) p += __shfl_xor(p, o, 64);
  float d = 1.0f / p;
  if ((t & 31) == 0) Dinv[(b * NH + (t >> 5)) * N_TOK + n] = d;
  float dv = d * 0.125f;
  float qs = 0.f;
  bf16x8 o8;
  #pragma unroll
  for (int u = 0; u < 8; ++u) {
    float qb_f = b2f(qv[u]) * dv;
    qs += qb_f;
    o8[u] = f2b(qb_f * sc);
  }
  *(bf16x8*)(qb + (size_t)R * HF + t * 8) = o8;
  #pragma unroll
  for (int o = 1; o < 64; o <<= 1) qs += __shfl_xor(qs, o, 64);
  if ((t & 63) == 0) wsum[t >> 6] = qs;
  __syncthreads();
  if (t == 0) rowc[R] = RATIO * FEPS * (wsum[0] + wsum[1] + wsum[2] + wsum[3]);
}

// ============ LayerNorm over D=512
template<bool OUT_BF16>
__global__ void ln_kernel(const float* __restrict__ x, const float* __restrict__ g,
                          const float* __restrict__ beta, void* __restrict__ y) {
  int row = blockIdx.x, t = threadIdx.x;
  __shared__ float red[4];
  __shared__ float bcast[2];
  const float* xr = x + (size_t)row * DM;
  float v0 = xr[t], v1 = xr[t + 256];
  float s = v0 + v1;
  #pragma unroll
  for (int o = 32; o > 0; o >>= 1) s += __shfl_xor(s, o, 64);
  if ((t & 63) == 0) red[t >> 6] = s;
  __syncthreads();
  if (t == 0) bcast[0] = (red[0] + red[1] + red[2] + red[3]) * (1.0f / 512.0f);
  __syncthreads();
  float mean = bcast[0];
  float d0 = v0 - mean, d1 = v1 - mean;
  float s2 = d0 * d0 + d1 * d1;
  #pragma unroll
  for (int o = 32; o > 0; o >>= 1) s2 += __shfl_xor(s2, o, 64);
  if ((t & 63) == 0) red[t >> 6] = s2;
  __syncthreads();
  if (t == 0) bcast[1] = (red[0] + red[1] + red[2] + red[3]) * (1.0f / 512.0f);
  __syncthreads();
  float inv = rsqrtf(bcast[1] + LN_EPS);
  float o0 = g[t] * d0 * inv + beta[t];
  float o1 = g[t + 256] * d1 * inv + beta[t + 256];
  if (OUT_BF16) {
    ((short*)y)[(size_t)row * DM + t] = f2b(o0);
    ((short*)y)[(size_t)row * DM + t + 256] = f2b(o1);
  } else {
    ((float*)y)[(size_t)row * DM + t] = o0;
    ((float*)y)[(size_t)row * DM + t + 256] = o1;
  }
}

extern "C" void kernel_launch(void* const* d_in, const int* in_sizes, int n_in,
                              void* d_out, int out_size, void* d_ws, size_t ws_size,
                              hipStream_t stream) {
  const float* x     = (const float*)d_in[0];
  const float* Wq    = (const float*)d_in[1];
  const float* bq    = (const float*)d_in[2];
  const float* Wk    = (const float*)d_in[3];
  const float* bk    = (const float*)d_in[4];
  const float* Wv    = (const float*)d_in[5];
  const float* bv    = (const float*)d_in[6];
  const float* Wo    = (const float*)d_in[7];
  const float* bo    = (const float*)d_in[8];
  const float* proj  = (const float*)d_in[9];
  const float* W1    = (const float*)d_in[10];
  const float* b1    = (const float*)d_in[11];
  const float* W2    = (const float*)d_in[12];
  const float* b2    = (const float*)d_in[13];
  const float* g1    = (const float*)d_in[14];
  const float* beta1 = (const float*)d_in[15];
  const float* g2    = (const float*)d_in[16];
  const float* beta2 = (const float*)d_in[17];

  float* ws = (float*)d_ws;
  float* y_out = (float*)d_out;
  float* attnw = y_out + (size_t)B_SZ * N_TOK * DM;

  float* ctxp  = ws + OFF_CTXP;
  short* qb    = (short*)(ws + OFF_QB);
  float* out2  = ws + OFF_OUT2;
  float* ff2   = ws + OFF_FF2;                // overlay of out2 (dead after ln1)
  short* ff1b  = (short*)(ws + OFF_FF1B);     // overlay of dead QKVlin
  short* qfb   = (short*)(ws + OFF_QFB);
  short* xb    = (short*)(ws + OFF_QFB);      // before qfb written
  short* kb    = (short*)(ws + OFF_KB);       // e = exp(dd - diag)
  short* Wqkvt = (short*)(ws + OFF_KB);       // before kb written
  float* QKVlin = ws + OFF_QKV;
  short* aob   = (short*)(ws + OFF_AOB);
  short* h1b   = (short*)(ws + OFF_H1B);
  short* Wot   = (short*)(ws + OFF_WOT);
  short* W1t   = (short*)(ws + OFF_W1T);
  short* W2t   = (short*)(ws + OFF_W2T);
  float* ksum  = ws + OFF_KSUM;
  float* Dinv  = ws + OFF_DINV;
  short* ctxT  = (short*)(ws + OFF_CTXT);
  float* bmax  = ws + OFF_BMAX;
  float* rowc  = ws + OFF_ROWC;
  float* part  = ws + OFF_PART;
  float* vsump = ws + OFF_VSUMP;

  dim3 blk(256);
  int MT = B_SZ * N_TOK;

  // 0) prep
  prep_kernel<<<1792, blk, 0, stream>>>(x, xb, Wq, Wk, Wv, Wo,
                                        Wqkvt, Wqkvt + 262144, Wqkvt + 524288, Wot,
                                        W1, W1t, W2, W2t);

  // 1) fused QKV projection
  gemm_mfma_qkv<<<dim3(LDQKV / 128, MT / 128), blk, 0, stream>>>(xb, Wqkvt, QKVlin);

  // 2) feature maps Q+K
  feat_mfma_kernel<<<dim3(N_TOK / 64, B_SZ * NH, 2), blk, 0, stream>>>(
      QKVlin, bq, bk, proj, qfb, kb, part, bmax);

  // 3) ctx partials (lean, z=16) + vsum blocks (x==4)  [last reader of QKVlin]
  ctx_part_kernel<<<dim3(5, B_SZ * NH, 16), blk, 0, stream>>>(kb, QKVlin, bv, ctxp, vsump);

  // 4) ksum finalize + ctx reduce
  smallfat_kernel<<<80, blk, 0, stream>>>(part, bmax, ksum, ctxp, vsump, ctxT);

  // 5) D_inv + q-scale + rowc
  dinvqs_kernel<<<MT, blk, 0, stream>>>(qfb, ksum, bmax, Dinv, rowc, qb);

  // 6) pv
  pv_kernel<<<dim3(N_TOK / 128 * B_SZ * NH), blk, 0, stream>>>(qfb, ctxT, Dinv, aob);

  // 7) Wo projection
  gemm_bn64_wo<<<dim3(DM / 64, MT / 128), blk, 0, stream>>>(aob, Wot, bo, out2);

  // 8) ln1
  ln_kernel<true><<<MT, blk, 0, stream>>>(out2, g1, beta1, h1b);

  // 9) fatB1: attnw z=0 (256) + ff1 (512); ff1b in dead-QKVlin region (no qb alias)
  fatB1_kernel<<<768, blk, 0, stream>>>(qb, kb, rowc, attnw, h1b, W1t, b1, ff1b);

  // 10) fatB2: attnw z=1 (256) + ff2 (256); ff2 in dead-out2 region
  fatB2_kernel<<<512, blk, 0, stream>>>(qb, kb, rowc, attnw, ff1b, W2t, b2, ff2);

  // 11) ln2
  ln_kernel<false><<<MT, blk, 0, stream>>>(ff2, g2, beta2, y_out);
}